// Round 5
// baseline (724.518 us; speedup 1.0000x reference)
//
#include <hip/hip_runtime.h>

typedef __attribute__((ext_vector_type(8))) short short8;
typedef __attribute__((ext_vector_type(4))) float f32x4;
typedef __attribute__((ext_vector_type(2))) float f32x2;

#define IMG_H 320
#define IMG_W 320
#define NBATCH 2
#define NFEAT 48
#define PLANE (IMG_H * IMG_W)          // 102400
#define KDIM 864                        // 9 taps * 96 channels
#define NDIM 96

// cconv tile params
#define TH 8
#define TW 32
#define FI 4                            // 16-row fragments per wave (wave M = 64)
#define BLK 512                         // 8 waves: 4 (wm) x 2 (wn)
#define HALO_H (TH + 2)                 // 10
#define HALO_W (TW + 2)                 // 34
#define HALO_PIX (HALO_H * HALO_W)      // 340
#define CPAD 104                        // 96 ch + 8 pad shorts per pixel row (208B, 16B aligned)
#define NCHUNK 12
#define STAGE_TOT (HALO_PIX * NCHUNK)   // 4080
#define ETS 33                          // epilogue LDS: tf[m*ETS + np], m<256, np<32

#define GRID 512                        // persistent grid: 2 blocks/CU x 256 CU, all resident
#define NTILE 800

__device__ __forceinline__ float sigma_f(float x) {
    float ax = __builtin_fabsf(x);
    float quad = x * x * 250.0f + 0.5f * x + 0.00025f;
    float rel = fmaxf(x, 0.0f);
    return ax > 0.001f ? rel : quad;
}

__device__ __forceinline__ unsigned short f2bf(float f) {
    union { float f; unsigned u; } v; v.f = f;
    unsigned r = (v.u + 0x7FFFu + ((v.u >> 16) & 1u)) >> 16;
    return (unsigned short)r;
}

__device__ __forceinline__ void nt_store2(float* p, float x, float y) {
    f32x2 v; v[0] = x; v[1] = y;
    __builtin_nontemporal_store(v, reinterpret_cast<f32x2*>(p));
}

// Device-scope grid barrier for persistent kernel (all GRID blocks resident).
__device__ __forceinline__ void grid_barrier(unsigned* cnt, unsigned gen, int tid) {
    __syncthreads();
    if (tid == 0) {
        __threadfence();                 // release: prior writes visible device-wide
        atomicAdd(cnt, 1u);
        unsigned target = GRID * gen;
        while (__atomic_load_n(cnt, __ATOMIC_ACQUIRE) < target)
            __builtin_amdgcn_s_sleep(8);
        __threadfence();                 // acquire side
    }
    __syncthreads();
}

// ---- device pieces ----

// wprep: both layers' Wt[n][k] bf16. n<48 -> yr of f=n, else yi of f=n-48;
// k = tap*96 + cp (cp<48 -> real ch cp, else imag ch cp-48).
__device__ __forceinline__ void wprep_piece(
    int idx,
    const float* __restrict__ wr1, const float* __restrict__ wi1,
    const float* __restrict__ wr2, const float* __restrict__ wi2,
    unsigned short* __restrict__ wt1, unsigned short* __restrict__ wt2) {
    if (idx >= 2 * NDIM * KDIM) return;
    int which = idx >= NDIM * KDIM;
    int id = which ? idx - NDIM * KDIM : idx;
    const float* wr = which ? wr2 : wr1;
    const float* wi = which ? wi2 : wi1;
    unsigned short* wt = which ? wt2 : wt1;
    int n = id / KDIM;
    int k = id - n * KDIM;
    int tap = k / 96;
    int cp = k - tap * 96;
    int f = (n < 48) ? n : n - 48;
    int c = (cp < 48) ? cp : cp - 48;
    int widx = (f * 48 + c) * 9 + tap;   // [F][Cin][3][3]
    float v;
    if (n < 48) v = (cp < 48) ?  wr[widx] : -wi[widx];
    else        v = (cp < 48) ?  wi[widx] :  wr[widx];
    wt[id] = f2bf(v);
}

// layer0: 1->48 complex conv at one pixel, writes fp32 out (+NHWC if nhwc != null)
template<int OUT_NHWC>
__device__ __forceinline__ void layer0_piece(
    int idx,
    const float* __restrict__ xr, const float* __restrict__ xi,
    const float* __restrict__ wr, const float* __restrict__ wi,
    const float* __restrict__ br, const float* __restrict__ bi,
    float* __restrict__ out, unsigned short* __restrict__ nhwc) {
    if (idx >= NBATCH * PLANE) return;
    int b = idx / PLANE;
    int p = idx - b * PLANE;
    int h = p / IMG_W;
    int w = p - h * IMG_W;
    const float* xrp = xr + (size_t)b * PLANE;
    const float* xip = xi + (size_t)b * PLANE;

    float ar[9], ai[9];
#pragma unroll
    for (int dy = 0; dy < 3; ++dy) {
#pragma unroll
        for (int dx = 0; dx < 3; ++dx) {
            int hh = h + dy - 1, ww = w + dx - 1;
            bool ok = ((unsigned)hh < (unsigned)IMG_H) && ((unsigned)ww < (unsigned)IMG_W);
            ar[dy * 3 + dx] = ok ? xrp[hh * IMG_W + ww] : 0.0f;
            ai[dy * 3 + dx] = ok ? xip[hh * IMG_W + ww] : 0.0f;
        }
    }

    short8 nh[12];
#pragma unroll
    for (int f = 0; f < NFEAT; ++f) {
        float yr = br[f], yi = bi[f];
#pragma unroll
        for (int t = 0; t < 9; ++t) {
            float wrv = wr[f * 9 + t], wiv = wi[f * 9 + t];
            yr += ar[t] * wrv - ai[t] * wiv;
            yi += ar[t] * wiv + ai[t] * wrv;
        }
        nt_store2(out + ((size_t)(b * NFEAT + f) * PLANE + p) * 2, yr, yi);
        if (OUT_NHWC) {
            nh[f >> 3][f & 7] = (short)f2bf(sigma_f(yr));
            nh[6 + (f >> 3)][f & 7] = (short)f2bf(sigma_f(yi));
        }
    }
    if (OUT_NHWC) {
        unsigned short* dst = nhwc + (size_t)(b * PLANE + p) * 96;
#pragma unroll
        for (int c = 0; c < 12; ++c)
            *reinterpret_cast<short8*>(dst + c * 8) = nh[c];
    }
}

// One 8x32 cconv output tile (implicit-GEMM 48->48 complex, bf16 MFMA 16x16x32).
// NHWC bf16 in, fp32 (+NHWC) out. Body identical to the verified R3 kernel.
template<int OUT_NHWC>
__device__ __forceinline__ void cconv_tile(
    int t0, const unsigned short* __restrict__ inH,
    const unsigned short* __restrict__ wt,   // [96][864] bf16
    const float* __restrict__ br, const float* __restrict__ bi,
    float* __restrict__ outF, unsigned short* __restrict__ outH,
    unsigned short* tile, int tid) {
    // XCD-aware bijective remap of the tile index
    int bid = (t0 & 7) * 100 + (t0 >> 3);
    int wblk = bid % (IMG_W / TW);          // 10
    int t = bid / (IMG_W / TW);
    int hblk = t % (IMG_H / TH);            // 40
    int b = t / (IMG_H / TH);
    int h0 = hblk * TH, w0 = wblk * TW;

    __syncthreads();   // previous tile's LDS reads complete before restaging

    // ---- stage halo tile (chunk-major: 12 chunks of 8 ch per pixel) ----
    {
        const unsigned short* inHb = inH + (size_t)b * PLANE * 96;
        short8 v[8];
        int dst[8];
#pragma unroll
        for (int s = 0; s < 8; ++s) {
            int it = tid + s * BLK;
            int pix = it / NCHUNK;
            int chunk = it - pix * NCHUNK;
            int hh = pix / HALO_W;
            int ww = pix - hh * HALO_W;
            int h = h0 + hh - 1, w = w0 + ww - 1;
            bool inimg = ((unsigned)h < (unsigned)IMG_H) && ((unsigned)w < (unsigned)IMG_W);
            bool live = it < STAGE_TOT;
            dst[s] = live ? (pix * CPAD + chunk * 8) : -1;
            if (live && inimg)
                v[s] = *reinterpret_cast<const short8*>(
                    inHb + ((size_t)(h * IMG_W + w) * 96 + chunk * 8));
            else
                v[s] = (short8){0, 0, 0, 0, 0, 0, 0, 0};
        }
#pragma unroll
        for (int s = 0; s < 8; ++s)
            if (dst[s] >= 0) *reinterpret_cast<short8*>(&tile[dst[s]]) = v[s];
    }
    __syncthreads();

    int wave = tid >> 6, lane = tid & 63;
    int wm = wave >> 1, wn = wave & 1;      // wm: 4 x 64-pix rows, wn: 48-col halves
    int lrow = lane & 15, lk = lane >> 4;

    int basepix[FI];
#pragma unroll
    for (int fi = 0; fi < FI; ++fi) {
        int m = wm * (FI * 16) + fi * 16 + lrow;
        basepix[fi] = (m >> 5) * HALO_W + (m & 31);
    }

    const unsigned short* wrow[3];
#pragma unroll
    for (int nf = 0; nf < 3; ++nf)
        wrow[nf] = wt + (size_t)(wn * 48 + nf * 16 + lrow) * KDIM + lk * 8;

    f32x4 acc[FI][3];
#pragma unroll
    for (int fi = 0; fi < FI; ++fi)
#pragma unroll
        for (int nf = 0; nf < 3; ++nf)
            acc[fi][nf] = (f32x4){0.f, 0.f, 0.f, 0.f};

    // double-buffered B prefetch over 27 (tap, cb) iterations
    short8 bf[2][3];
#pragma unroll
    for (int nf = 0; nf < 3; ++nf)
        bf[0][nf] = *reinterpret_cast<const short8*>(wrow[nf]);

#pragma unroll
    for (int it = 0; it < 27; ++it) {
        const int cur = it & 1;
        const int tap = it / 3, cb = it - tap * 3;
        if (it < 26) {
            const int it2 = it + 1;
            const int tap2 = it2 / 3, cb2 = it2 - tap2 * 3;
#pragma unroll
            for (int nf = 0; nf < 3; ++nf)
                bf[cur ^ 1][nf] = *reinterpret_cast<const short8*>(wrow[nf] + tap2 * 96 + cb2 * 32);
        }
        const int tapoff = (tap / 3) * HALO_W + (tap % 3);
#pragma unroll
        for (int fi = 0; fi < FI; ++fi) {
            short8 a = *reinterpret_cast<const short8*>(
                &tile[(basepix[fi] + tapoff) * CPAD + cb * 32 + lk * 8]);
#pragma unroll
            for (int nf = 0; nf < 3; ++nf)
                acc[fi][nf] = __builtin_amdgcn_mfma_f32_16x16x32_bf16(a, bf[cur][nf], acc[fi][nf], 0, 0, 0);
        }
    }

    // ---- epilogue ----
#pragma unroll
    for (int nf = 0; nf < 3; ++nf) {
        int f = nf * 16 + lrow;
        float bias = wn ? bi[f] : br[f];
#pragma unroll
        for (int fi = 0; fi < FI; ++fi)
#pragma unroll
            for (int j = 0; j < 4; ++j)
                acc[fi][nf][j] += bias;
    }

    float* tf = reinterpret_cast<float*>(tile);
    int fl = tid >> 5;          // 0..15
    int p0 = tid & 31;
    int ep = tid >> 1;          // epilogue pixel 0..255
    int ehf = tid & 1;          // 0: re chunks 0-5, 1: im chunks 6-11
    short8 nh[6];
    __syncthreads();            // all A-reads done before reusing tile

#pragma unroll
    for (int r = 0; r < 3; ++r) {
        int np = wn * 16 + lrow;
#pragma unroll
        for (int fi = 0; fi < FI; ++fi) {
            int m0 = wm * (FI * 16) + fi * 16 + lk * 4;
#pragma unroll
            for (int j = 0; j < 4; ++j)
                tf[(m0 + j) * ETS + np] = acc[fi][r][j];
        }
        __syncthreads();
        // fp32 out: 16 f x {re,im} x 256 pix, float2-coalesced, non-temporal
        float* obase = outF + (((size_t)(b * NFEAT + r * 16 + fl) * IMG_H + h0) * IMG_W + w0) * 2;
#pragma unroll
        for (int g = 0; g < TH; ++g)
            nt_store2(obase + ((size_t)g * IMG_W + p0) * 2,
                      tf[(g * 32 + p0) * ETS + fl],
                      tf[(g * 32 + p0) * ETS + 16 + fl]);
        if (OUT_NHWC) {
#pragma unroll
            for (int ci = 0; ci < 2; ++ci) {
                short8 v;
#pragma unroll
                for (int u = 0; u < 8; ++u)
                    v[u] = (short)f2bf(sigma_f(tf[ep * ETS + ehf * 16 + ci * 8 + u]));
                nh[r * 2 + ci] = v;
            }
        }
        if (r < 2) __syncthreads();
    }
    if (OUT_NHWC) {
        int h = h0 + (ep >> 5), w = w0 + (ep & 31);
        unsigned short* dst = outH + (size_t)(b * PLANE + h * IMG_W + w) * 96 + ehf * 48;
#pragma unroll
        for (int c = 0; c < 6; ++c)
            *reinterpret_cast<short8*>(dst + c * 8) = nh[c];
    }
}

// ---- fused persistent kernel (fast path) ----
__global__ __launch_bounds__(BLK, 4) void fused_kernel(
    const float* __restrict__ xr, const float* __restrict__ xi,
    const float* __restrict__ w0r, const float* __restrict__ w0i,
    const float* __restrict__ b0r, const float* __restrict__ b0i,
    const float* __restrict__ w1r, const float* __restrict__ w1i,
    const float* __restrict__ b1r, const float* __restrict__ b1i,
    const float* __restrict__ w2r, const float* __restrict__ w2i,
    const float* __restrict__ b2r, const float* __restrict__ b2i,
    float* __restrict__ out,
    unsigned short* __restrict__ wt1, unsigned short* __restrict__ wt2,
    unsigned short* __restrict__ nhwc0, unsigned short* __restrict__ nhwc1,
    unsigned* __restrict__ cnt) {
    __shared__ __align__(16) unsigned short tile[HALO_PIX * CPAD];  // 70720 B
    const int tid = threadIdx.x;
    const int bid = blockIdx.x;
    const size_t layer_sz = (size_t)NBATCH * NFEAT * PLANE * 2;

    // phase 0: weight prep + layer 0 (grid-stride, single pass each)
    wprep_piece(bid * BLK + tid, w1r, w1i, w2r, w2i, wt1, wt2);
    layer0_piece<1>(bid * BLK + tid, xr, xi, w0r, w0i, b0r, b0i, out, nhwc0);
    grid_barrier(cnt, 1, tid);

    // phase 1: cconv layer 1 (NHWC out for layer 2)
    for (int t = bid; t < NTILE; t += GRID)
        cconv_tile<1>(t, nhwc0, wt1, b1r, b1i, out + layer_sz, nhwc1, tile, tid);
    grid_barrier(cnt, 2, tid);

    // phase 2: cconv layer 2 (fp32 out only)
    for (int t = bid; t < NTILE; t += GRID)
        cconv_tile<0>(t, nhwc1, wt2, b2r, b2i, out + 2 * layer_sz, nullptr, tile, tid);
}

// ---- standalone fallback kernels (workspace too small for NHWC intermediates) ----
__global__ void wprep_kernel(const float* __restrict__ wr1, const float* __restrict__ wi1,
                             const float* __restrict__ wr2, const float* __restrict__ wi2,
                             unsigned short* __restrict__ wt1, unsigned short* __restrict__ wt2) {
    wprep_piece(blockIdx.x * 256 + threadIdx.x, wr1, wi1, wr2, wi2, wt1, wt2);
}

__global__ __launch_bounds__(256) void layer0_kernel(
    const float* __restrict__ xr, const float* __restrict__ xi,
    const float* __restrict__ wr, const float* __restrict__ wi,
    const float* __restrict__ br, const float* __restrict__ bi,
    float* __restrict__ out) {
    layer0_piece<0>(blockIdx.x * 256 + threadIdx.x, xr, xi, wr, wi, br, bi, out, nullptr);
}

// fallback cconv: fp32 interleaved pre-act input (sigma on load), fp32 out
__global__ __launch_bounds__(BLK, 4) void cconv_kernel(
    const float* __restrict__ inF,
    const unsigned short* __restrict__ wt,
    const float* __restrict__ br, const float* __restrict__ bi,
    float* __restrict__ outF) {
    __shared__ __align__(16) unsigned short tile[HALO_PIX * CPAD];

    int bid0 = blockIdx.x;
    int bid = (bid0 & 7) * 100 + (bid0 >> 3);
    int wblk = bid % (IMG_W / TW);
    int t = bid / (IMG_W / TW);
    int hblk = t % (IMG_H / TH);
    int b = t / (IMG_H / TH);
    int h0 = hblk * TH, w0 = wblk * TW;
    int tid = threadIdx.x;

    {
        const float* inFb = inF + (size_t)b * NFEAT * PLANE * 2;
        for (int it = tid; it < STAGE_TOT; it += BLK) {
            int pix = it / NCHUNK;
            int chunk = it - pix * NCHUNK;
            int hh = pix / HALO_W;
            int ww = pix - hh * HALO_W;
            int h = h0 + hh - 1, w = w0 + ww - 1;
            bool ok = ((unsigned)h < (unsigned)IMG_H) && ((unsigned)w < (unsigned)IMG_W);
            int c0 = chunk * 8;
            short8 v;
#pragma unroll
            for (int j = 0; j < 8; ++j) {
                int cp = c0 + j;
                int c = (cp < 48) ? cp : cp - 48;
                int ri = (cp < 48) ? 0 : 1;
                float x = ok ? inFb[((size_t)c * PLANE + h * IMG_W + w) * 2 + ri] : 0.0f;
                v[j] = (short)f2bf(sigma_f(x));
            }
            *reinterpret_cast<short8*>(&tile[pix * CPAD + chunk * 8]) = v;
        }
    }
    __syncthreads();

    int wave = tid >> 6, lane = tid & 63;
    int wm = wave >> 1, wn = wave & 1;
    int lrow = lane & 15, lk = lane >> 4;

    int basepix[FI];
#pragma unroll
    for (int fi = 0; fi < FI; ++fi) {
        int m = wm * (FI * 16) + fi * 16 + lrow;
        basepix[fi] = (m >> 5) * HALO_W + (m & 31);
    }
    const unsigned short* wrow[3];
#pragma unroll
    for (int nf = 0; nf < 3; ++nf)
        wrow[nf] = wt + (size_t)(wn * 48 + nf * 16 + lrow) * KDIM + lk * 8;

    f32x4 acc[FI][3];
#pragma unroll
    for (int fi = 0; fi < FI; ++fi)
#pragma unroll
        for (int nf = 0; nf < 3; ++nf)
            acc[fi][nf] = (f32x4){0.f, 0.f, 0.f, 0.f};

    short8 bf[2][3];
#pragma unroll
    for (int nf = 0; nf < 3; ++nf)
        bf[0][nf] = *reinterpret_cast<const short8*>(wrow[nf]);

#pragma unroll
    for (int it = 0; it < 27; ++it) {
        const int cur = it & 1;
        const int tap = it / 3, cb = it - tap * 3;
        if (it < 26) {
            const int it2 = it + 1;
            const int tap2 = it2 / 3, cb2 = it2 - tap2 * 3;
#pragma unroll
            for (int nf = 0; nf < 3; ++nf)
                bf[cur ^ 1][nf] = *reinterpret_cast<const short8*>(wrow[nf] + tap2 * 96 + cb2 * 32);
        }
        const int tapoff = (tap / 3) * HALO_W + (tap % 3);
#pragma unroll
        for (int fi = 0; fi < FI; ++fi) {
            short8 a = *reinterpret_cast<const short8*>(
                &tile[(basepix[fi] + tapoff) * CPAD + cb * 32 + lk * 8]);
#pragma unroll
            for (int nf = 0; nf < 3; ++nf)
                acc[fi][nf] = __builtin_amdgcn_mfma_f32_16x16x32_bf16(a, bf[cur][nf], acc[fi][nf], 0, 0, 0);
        }
    }

#pragma unroll
    for (int nf = 0; nf < 3; ++nf) {
        int f = nf * 16 + lrow;
        float bias = wn ? bi[f] : br[f];
#pragma unroll
        for (int fi = 0; fi < FI; ++fi)
#pragma unroll
            for (int j = 0; j < 4; ++j)
                acc[fi][nf][j] += bias;
    }

    float* tf = reinterpret_cast<float*>(tile);
    int fl = tid >> 5;
    int p0 = tid & 31;
    __syncthreads();

#pragma unroll
    for (int r = 0; r < 3; ++r) {
        int np = wn * 16 + lrow;
#pragma unroll
        for (int fi = 0; fi < FI; ++fi) {
            int m0 = wm * (FI * 16) + fi * 16 + lk * 4;
#pragma unroll
            for (int j = 0; j < 4; ++j)
                tf[(m0 + j) * ETS + np] = acc[fi][r][j];
        }
        __syncthreads();
        float* obase = outF + (((size_t)(b * NFEAT + r * 16 + fl) * IMG_H + h0) * IMG_W + w0) * 2;
#pragma unroll
        for (int g = 0; g < TH; ++g)
            nt_store2(obase + ((size_t)g * IMG_W + p0) * 2,
                      tf[(g * 32 + p0) * ETS + fl],
                      tf[(g * 32 + p0) * ETS + 16 + fl]);
        if (r < 2) __syncthreads();
    }
}

extern "C" void kernel_launch(void* const* d_in, const int* in_sizes, int n_in,
                              void* d_out, int out_size, void* d_ws, size_t ws_size,
                              hipStream_t stream) {
    const float* x_real  = (const float*)d_in[0];
    const float* x_imag  = (const float*)d_in[1];
    const float* w0_real = (const float*)d_in[2];
    const float* w0_imag = (const float*)d_in[3];
    const float* b0_real = (const float*)d_in[4];
    const float* b0_imag = (const float*)d_in[5];
    const float* w1_real = (const float*)d_in[6];
    const float* w1_imag = (const float*)d_in[7];
    const float* b1_real = (const float*)d_in[8];
    const float* b1_imag = (const float*)d_in[9];
    const float* w2_real = (const float*)d_in[10];
    const float* w2_imag = (const float*)d_in[11];
    const float* b2_real = (const float*)d_in[12];
    const float* b2_imag = (const float*)d_in[13];

    float* out = (float*)d_out;
    unsigned short* wt1 = (unsigned short*)d_ws;
    unsigned short* wt2 = wt1 + NDIM * KDIM;

    const size_t wt_bytes = (size_t)2 * NDIM * KDIM * 2;             // 331776
    const size_t cnt_bytes = 256;
    const size_t nhwc_elems = (size_t)NBATCH * PLANE * 96;           // 19,660,800 bf16
    const size_t need = wt_bytes + cnt_bytes + 2 * nhwc_elems * 2;   // ~75.3 MiB
    const bool fast = ws_size >= need;

    unsigned* cnt = (unsigned*)((char*)d_ws + wt_bytes);
    unsigned short* nhwc0 = (unsigned short*)((char*)d_ws + wt_bytes + cnt_bytes);
    unsigned short* nhwc1 = nhwc0 + nhwc_elems;

    const size_t layer_sz = (size_t)NBATCH * NFEAT * PLANE * 2;      // floats per layer

    if (fast) {
        (void)hipMemsetAsync(cnt, 0, cnt_bytes, stream);
        fused_kernel<<<GRID, BLK, 0, stream>>>(
            x_real, x_imag,
            w0_real, w0_imag, b0_real, b0_imag,
            w1_real, w1_imag, b1_real, b1_imag,
            w2_real, w2_imag, b2_real, b2_imag,
            out, wt1, wt2, nhwc0, nhwc1, cnt);
    } else {
        wprep_kernel<<<(2 * NDIM * KDIM + 255) / 256, 256, 0, stream>>>(
            w1_real, w1_imag, w2_real, w2_imag, wt1, wt2);
        const int l0_grid = NBATCH * PLANE / 256;                    // 800
        const int conv_grid = NBATCH * (IMG_H / TH) * (IMG_W / TW);  // 800
        layer0_kernel<<<l0_grid, 256, 0, stream>>>(
            x_real, x_imag, w0_real, w0_imag, b0_real, b0_imag, out);
        cconv_kernel<<<conv_grid, BLK, 0, stream>>>(
            out, wt1, b1_real, b1_imag, out + layer_sz);
        cconv_kernel<<<conv_grid, BLK, 0, stream>>>(
            out + layer_sz, wt2, b2_real, b2_imag, out + 2 * layer_sz);
    }
}

// Round 6
// 168.037 us; speedup vs baseline: 4.3116x; 4.3116x over previous
//
#include <hip/hip_runtime.h>

typedef __attribute__((ext_vector_type(8))) short short8;
typedef __attribute__((ext_vector_type(4))) float f32x4;

#define IMG_H 320
#define IMG_W 320
#define NBATCH 2
#define NFEAT 48
#define PLANE (IMG_H * IMG_W)          // 102400
#define KDIM 864                        // 9 taps * 96 channels
#define NDIM 96

// cconv tile params
#define TH 8
#define TW 32
#define FI 4                            // 16-row fragments per wave (wave M = 64)
#define BLK 512                         // 8 waves: 4 (wm) x 2 (wn)
#define HALO_H (TH + 2)                 // 10
#define HALO_W (TW + 2)                 // 34
#define HALO_PIX (HALO_H * HALO_W)      // 340
#define CPAD 104                        // 96 ch + 8 pad shorts per pixel row (208B, 16B aligned)
#define NCHUNK 12
#define STAGE_TOT (HALO_PIX * NCHUNK)   // 4080
#define ETS 33                          // epilogue LDS: tf[m*ETS + np], m<256, np<32

__device__ __forceinline__ float sigma_f(float x) {
    float ax = __builtin_fabsf(x);
    float quad = x * x * 250.0f + 0.5f * x + 0.00025f;
    float rel = fmaxf(x, 0.0f);
    return ax > 0.001f ? rel : quad;
}

__device__ __forceinline__ unsigned short f2bf(float f) {
    union { float f; unsigned u; } v; v.f = f;
    unsigned r = (v.u + 0x7FFFu + ((v.u >> 16) & 1u)) >> 16;
    return (unsigned short)r;
}

// wprep: both layers' Wt[n][k] bf16. n<48 -> yr of f=n, else yi of f=n-48;
// k = tap*96 + cp (cp<48 -> real ch cp, else imag ch cp-48).
__device__ __forceinline__ void wprep_piece(
    int idx,
    const float* __restrict__ wr1, const float* __restrict__ wi1,
    const float* __restrict__ wr2, const float* __restrict__ wi2,
    unsigned short* __restrict__ wt1, unsigned short* __restrict__ wt2) {
    if (idx >= 2 * NDIM * KDIM) return;
    int which = idx >= NDIM * KDIM;
    int id = which ? idx - NDIM * KDIM : idx;
    const float* wr = which ? wr2 : wr1;
    const float* wi = which ? wi2 : wi1;
    unsigned short* wt = which ? wt2 : wt1;
    int n = id / KDIM;
    int k = id - n * KDIM;
    int tap = k / 96;
    int cp = k - tap * 96;
    int f = (n < 48) ? n : n - 48;
    int c = (cp < 48) ? cp : cp - 48;
    int widx = (f * 48 + c) * 9 + tap;   // [F][Cin][3][3]
    float v;
    if (n < 48) v = (cp < 48) ?  wr[widx] : -wi[widx];
    else        v = (cp < 48) ?  wi[widx] :  wr[widx];
    wt[id] = f2bf(v);
}

// Layer 0: 1->48 complex conv, thread-per-pixel over ALL f.
// Also folds both cconv layers' weight prep into this dispatch (idx < 165888).
template<int OUT_NHWC>
__global__ __launch_bounds__(256) void layer0_kernel(
    const float* __restrict__ xr, const float* __restrict__ xi,
    const float* __restrict__ wr, const float* __restrict__ wi,
    const float* __restrict__ br, const float* __restrict__ bi,
    const float* __restrict__ w1r, const float* __restrict__ w1i,
    const float* __restrict__ w2r, const float* __restrict__ w2i,
    unsigned short* __restrict__ wt1, unsigned short* __restrict__ wt2,
    float* __restrict__ out, unsigned short* __restrict__ nhwc) {
    int idx = blockIdx.x * 256 + threadIdx.x;        // 204800 pixels total
    wprep_piece(idx, w1r, w1i, w2r, w2i, wt1, wt2);

    int b = idx / PLANE;
    int p = idx - b * PLANE;
    int h = p / IMG_W;
    int w = p - h * IMG_W;
    const float* xrp = xr + (size_t)b * PLANE;
    const float* xip = xi + (size_t)b * PLANE;

    float ar[9], ai[9];
#pragma unroll
    for (int dy = 0; dy < 3; ++dy) {
#pragma unroll
        for (int dx = 0; dx < 3; ++dx) {
            int hh = h + dy - 1, ww = w + dx - 1;
            bool ok = ((unsigned)hh < (unsigned)IMG_H) && ((unsigned)ww < (unsigned)IMG_W);
            ar[dy * 3 + dx] = ok ? xrp[hh * IMG_W + ww] : 0.0f;
            ai[dy * 3 + dx] = ok ? xip[hh * IMG_W + ww] : 0.0f;
        }
    }

    short8 nh[12];
#pragma unroll
    for (int f = 0; f < NFEAT; ++f) {
        float yr = br[f], yi = bi[f];
#pragma unroll
        for (int t = 0; t < 9; ++t) {
            float wrv = wr[f * 9 + t], wiv = wi[f * 9 + t];
            yr += ar[t] * wrv - ai[t] * wiv;
            yi += ar[t] * wiv + ai[t] * wrv;
        }
        float2 o; o.x = yr; o.y = yi;
        *reinterpret_cast<float2*>(out + ((size_t)(b * NFEAT + f) * PLANE + p) * 2) = o;
        if (OUT_NHWC) {
            nh[f >> 3][f & 7] = (short)f2bf(sigma_f(yr));
            nh[6 + (f >> 3)][f & 7] = (short)f2bf(sigma_f(yi));
        }
    }
    if (OUT_NHWC) {
        unsigned short* dst = nhwc + (size_t)(b * PLANE + p) * 96;
#pragma unroll
        for (int c = 0; c < 12; ++c)
            *reinterpret_cast<short8*>(dst + c * 8) = nh[c];
    }
}

// Layers 1/2: implicit-GEMM complex conv 48->48, bf16 MFMA.
// IN_MODE: 0 = fp32 interleaved pre-act (sigma on load), 1 = bf16 NHWC post-act.
template<int IN_MODE, int OUT_NHWC>
__global__ __launch_bounds__(BLK, 4) void cconv_kernel(
    const float* __restrict__ inF, const unsigned short* __restrict__ inH,
    const unsigned short* __restrict__ wt,   // [96][864] bf16
    const float* __restrict__ br, const float* __restrict__ bi,
    float* __restrict__ outF, unsigned short* __restrict__ outH) {
    __shared__ __align__(16) unsigned short tile[HALO_PIX * CPAD];  // 70720 B

    // XCD-aware swizzle: grid = 800 = 8 * 100, bijective chunked remap
    int bid0 = blockIdx.x;
    int bid = (bid0 & 7) * 100 + (bid0 >> 3);
    int wblk = bid % (IMG_W / TW);          // 10
    int t = bid / (IMG_W / TW);
    int hblk = t % (IMG_H / TH);            // 40
    int b = t / (IMG_H / TH);
    int h0 = hblk * TH, w0 = wblk * TW;

    int tid = threadIdx.x;

    // ---- stage halo tile (chunk-major: 12 chunks of 8 ch per pixel) ----
    if (IN_MODE == 1) {
        const unsigned short* inHb = inH + (size_t)b * PLANE * 96;
        short8 v[8];
        int dst[8];
#pragma unroll
        for (int s = 0; s < 8; ++s) {
            int it = tid + s * BLK;
            int pix = it / NCHUNK;
            int chunk = it - pix * NCHUNK;
            int hh = pix / HALO_W;
            int ww = pix - hh * HALO_W;
            int h = h0 + hh - 1, w = w0 + ww - 1;
            bool inimg = ((unsigned)h < (unsigned)IMG_H) && ((unsigned)w < (unsigned)IMG_W);
            bool live = it < STAGE_TOT;
            dst[s] = live ? (pix * CPAD + chunk * 8) : -1;
            if (live && inimg)
                v[s] = *reinterpret_cast<const short8*>(
                    inHb + ((size_t)(h * IMG_W + w) * 96 + chunk * 8));
            else
                v[s] = (short8){0, 0, 0, 0, 0, 0, 0, 0};
        }
#pragma unroll
        for (int s = 0; s < 8; ++s)
            if (dst[s] >= 0) *reinterpret_cast<short8*>(&tile[dst[s]]) = v[s];
    } else {
        const float* inFb = inF + (size_t)b * NFEAT * PLANE * 2;
        for (int it = tid; it < STAGE_TOT; it += BLK) {
            int pix = it / NCHUNK;
            int chunk = it - pix * NCHUNK;
            int hh = pix / HALO_W;
            int ww = pix - hh * HALO_W;
            int h = h0 + hh - 1, w = w0 + ww - 1;
            bool ok = ((unsigned)h < (unsigned)IMG_H) && ((unsigned)w < (unsigned)IMG_W);
            int c0 = chunk * 8;
            short8 v;
#pragma unroll
            for (int j = 0; j < 8; ++j) {
                int cp = c0 + j;
                int c = (cp < 48) ? cp : cp - 48;
                int ri = (cp < 48) ? 0 : 1;
                float x = ok ? inFb[((size_t)c * PLANE + h * IMG_W + w) * 2 + ri] : 0.0f;
                v[j] = (short)f2bf(sigma_f(x));
            }
            *reinterpret_cast<short8*>(&tile[pix * CPAD + chunk * 8]) = v;
        }
    }
    __syncthreads();

    int wave = tid >> 6, lane = tid & 63;
    int wm = wave >> 1, wn = wave & 1;      // wm: 4 x 64-pix rows, wn: 48-col halves
    int lrow = lane & 15, lk = lane >> 4;

    int basepix[FI];
#pragma unroll
    for (int fi = 0; fi < FI; ++fi) {
        int m = wm * (FI * 16) + fi * 16 + lrow;
        basepix[fi] = (m >> 5) * HALO_W + (m & 31);
    }

    const unsigned short* wrow[3];
#pragma unroll
    for (int nf = 0; nf < 3; ++nf)
        wrow[nf] = wt + (size_t)(wn * 48 + nf * 16 + lrow) * KDIM + lk * 8;

    f32x4 acc[FI][3];
#pragma unroll
    for (int fi = 0; fi < FI; ++fi)
#pragma unroll
        for (int nf = 0; nf < 3; ++nf)
            acc[fi][nf] = (f32x4){0.f, 0.f, 0.f, 0.f};

    // double-buffered B prefetch over 27 (tap, cb) iterations
    short8 bf[2][3];
#pragma unroll
    for (int nf = 0; nf < 3; ++nf)
        bf[0][nf] = *reinterpret_cast<const short8*>(wrow[nf]);

#pragma unroll
    for (int it = 0; it < 27; ++it) {
        const int cur = it & 1;
        const int tap = it / 3, cb = it - tap * 3;
        if (it < 26) {
            const int it2 = it + 1;
            const int tap2 = it2 / 3, cb2 = it2 - tap2 * 3;
#pragma unroll
            for (int nf = 0; nf < 3; ++nf)
                bf[cur ^ 1][nf] = *reinterpret_cast<const short8*>(wrow[nf] + tap2 * 96 + cb2 * 32);
        }
        const int tapoff = (tap / 3) * HALO_W + (tap % 3);
#pragma unroll
        for (int fi = 0; fi < FI; ++fi) {
            short8 a = *reinterpret_cast<const short8*>(
                &tile[(basepix[fi] + tapoff) * CPAD + cb * 32 + lk * 8]);
#pragma unroll
            for (int nf = 0; nf < 3; ++nf)
                acc[fi][nf] = __builtin_amdgcn_mfma_f32_16x16x32_bf16(a, bf[cur][nf], acc[fi][nf], 0, 0, 0);
        }
    }

    // ---- epilogue ----
    // D mapping: col (N) = lrow, row (M) = lk*4 + j within each 16x16 frag.
    // Bias into acc, then 3 transpose rounds through LDS tf[m*ETS + np]
    // (m = tile pixel 0..255, np = 0..15 re / 16..31 im of this round's f-group).
    // fp32 global writes float2-coalesced; NHWC accumulated in registers
    // (thread = pixel tid>>1, half tid&1) and written as ONE 96B-contiguous
    // store per thread at the end.
#pragma unroll
    for (int nf = 0; nf < 3; ++nf) {
        int f = nf * 16 + lrow;
        float bias = wn ? bi[f] : br[f];
#pragma unroll
        for (int fi = 0; fi < FI; ++fi)
#pragma unroll
            for (int j = 0; j < 4; ++j)
                acc[fi][nf][j] += bias;
    }

    float* tf = reinterpret_cast<float*>(tile);
    int fl = tid >> 5;          // 0..15
    int p0 = tid & 31;
    int ep = tid >> 1;          // epilogue pixel 0..255
    int ehf = tid & 1;          // 0: re chunks 0-5, 1: im chunks 6-11
    short8 nh[6];
    __syncthreads();            // all A-reads done before reusing tile

#pragma unroll
    for (int r = 0; r < 3; ++r) {
        int np = wn * 16 + lrow;
#pragma unroll
        for (int fi = 0; fi < FI; ++fi) {
            int m0 = wm * (FI * 16) + fi * 16 + lk * 4;
#pragma unroll
            for (int j = 0; j < 4; ++j)
                tf[(m0 + j) * ETS + np] = acc[fi][r][j];
        }
        __syncthreads();
        // fp32 out: 16 f x {re,im} x 256 pix, float2-coalesced
        float* obase = outF + (((size_t)(b * NFEAT + r * 16 + fl) * IMG_H + h0) * IMG_W + w0) * 2;
#pragma unroll
        for (int g = 0; g < TH; ++g) {
            float2 o;
            o.x = tf[(g * 32 + p0) * ETS + fl];
            o.y = tf[(g * 32 + p0) * ETS + 16 + fl];
            *reinterpret_cast<float2*>(obase + ((size_t)g * IMG_W + p0) * 2) = o;
        }
        if (OUT_NHWC) {
            // this round contributes chunks {2r,2r+1} (re) / {6+2r,7+2r} (im)
#pragma unroll
            for (int ci = 0; ci < 2; ++ci) {
                short8 v;
#pragma unroll
                for (int u = 0; u < 8; ++u)
                    v[u] = (short)f2bf(sigma_f(tf[ep * ETS + ehf * 16 + ci * 8 + u]));
                nh[r * 2 + ci] = v;
            }
        }
        if (r < 2) __syncthreads();
    }
    if (OUT_NHWC) {
        int h = h0 + (ep >> 5), w = w0 + (ep & 31);
        unsigned short* dst = outH + (size_t)(b * PLANE + h * IMG_W + w) * 96 + ehf * 48;
#pragma unroll
        for (int c = 0; c < 6; ++c)
            *reinterpret_cast<short8*>(dst + c * 8) = nh[c];
    }
}

extern "C" void kernel_launch(void* const* d_in, const int* in_sizes, int n_in,
                              void* d_out, int out_size, void* d_ws, size_t ws_size,
                              hipStream_t stream) {
    const float* x_real  = (const float*)d_in[0];
    const float* x_imag  = (const float*)d_in[1];
    const float* w0_real = (const float*)d_in[2];
    const float* w0_imag = (const float*)d_in[3];
    const float* b0_real = (const float*)d_in[4];
    const float* b0_imag = (const float*)d_in[5];
    const float* w1_real = (const float*)d_in[6];
    const float* w1_imag = (const float*)d_in[7];
    const float* b1_real = (const float*)d_in[8];
    const float* b1_imag = (const float*)d_in[9];
    const float* w2_real = (const float*)d_in[10];
    const float* w2_imag = (const float*)d_in[11];
    const float* b2_real = (const float*)d_in[12];
    const float* b2_imag = (const float*)d_in[13];

    float* out = (float*)d_out;
    unsigned short* wt1 = (unsigned short*)d_ws;
    unsigned short* wt2 = wt1 + NDIM * KDIM;

    const size_t wt_bytes = (size_t)2 * NDIM * KDIM * 2;             // 331776
    const size_t nhwc_elems = (size_t)NBATCH * PLANE * 96;           // 19,660,800 bf16
    const size_t need = wt_bytes + 2 * nhwc_elems * 2;               // ~75.3 MiB
    const bool fast = ws_size >= need;

    unsigned short* nhwc0 = (unsigned short*)((char*)d_ws + wt_bytes);
    unsigned short* nhwc1 = nhwc0 + nhwc_elems;

    const size_t layer_sz = (size_t)NBATCH * NFEAT * PLANE * 2;      // floats per layer

    const int l0_grid = NBATCH * PLANE / 256;                        // 800
    const int conv_grid = NBATCH * (IMG_H / TH) * (IMG_W / TW);      // 800

    if (fast) {
        layer0_kernel<1><<<l0_grid, 256, 0, stream>>>(
            x_real, x_imag, w0_real, w0_imag, b0_real, b0_imag,
            w1_real, w1_imag, w2_real, w2_imag, wt1, wt2, out, nhwc0);
        cconv_kernel<1, 1><<<conv_grid, BLK, 0, stream>>>(
            nullptr, nhwc0, wt1, b1_real, b1_imag, out + layer_sz, nhwc1);
        cconv_kernel<1, 0><<<conv_grid, BLK, 0, stream>>>(
            nullptr, nhwc1, wt2, b2_real, b2_imag, out + 2 * layer_sz, nullptr);
    } else {
        layer0_kernel<0><<<l0_grid, 256, 0, stream>>>(
            x_real, x_imag, w0_real, w0_imag, b0_real, b0_imag,
            w1_real, w1_imag, w2_real, w2_imag, wt1, wt2, out, nullptr);
        cconv_kernel<0, 0><<<conv_grid, BLK, 0, stream>>>(
            out, nullptr, wt1, b1_real, b1_imag, out + layer_sz, nullptr);
        cconv_kernel<0, 0><<<conv_grid, BLK, 0, stream>>>(
            out + layer_sz, nullptr, wt2, b2_real, b2_imag, out + 2 * layer_sz, nullptr);
    }
}